// Round 5
// baseline (256.368 us; speedup 1.0000x reference)
//
#include <hip/hip_runtime.h>
#include <math.h>

#define BB 16
#define QQ 300
#define CC 256
#define NHH 8
#define SSS 8500
#define GQ 10
#define QT (QQ / GQ) // 30

// ---------------------------------------------------------------------------
// Fully fused kernel: per block = (batch b, 10-query tile).
// 640 threads = 10 waves.
//   Stage 1 (GEMM, waves 0..5): t<256 -> offset col t (h,p,xy) for 10
//     queries; 256<=t<384 -> attn logit col + 16-lane-shuffle softmax.
//     Results go straight to LDS (loc in [q][p*8+h] float2, attn likewise) —
//     no global round-trip. attn also written to d_out (required output).
//   Stage 2 (weights, all threads): one task per (q,h,p): bilinear weights
//     (attn folded, OOB zeroed) + 4 clamped corner byte-offsets -> LDS.
//   Stage 3 (gather, wave=query): per point 2 ds_read_b128 + 4 float4
//     gathers + 16 FMAs; float4 store of the head-chunk.
// XCD swizzle: b = blockIdx % 16 so batch b's 8.7 MB value slab maps to one
// XCD's L2 (blockIdx%8 fixed per batch).
// ---------------------------------------------------------------------------
__global__ __launch_bounds__(640) void fused_kernel(
    const float* __restrict__ hs,      // (B,Q,C)
    const float* __restrict__ enc,     // (B,S,256)
    const float* __restrict__ refp,    // (B,Q,1,4)
    const float* __restrict__ off_k,   // (C,256)
    const float* __restrict__ off_b,   // 256
    const float* __restrict__ attn_k,  // (C,128)
    const float* __restrict__ attn_b,  // 128
    const float* __restrict__ nps,     // 16
    float* __restrict__ out,           // (B,Q,256)
    float* __restrict__ attn_out)      // (B,Q,128) [h][p]
{
    __shared__ float  sh_l[GQ * 128 * 2];  // [q][p*8+h][xy]
    __shared__ float  sh_a[GQ * 128];      // [q][p*8+h]
    __shared__ float4 sh_w[GQ * 128];      // [q][p*8+h] weights
    __shared__ int4   sh_o[GQ * 128];      // [q][p*8+h] byte offsets

    const int t = threadIdx.x;
    const int blk = blockIdx.x;            // 0..479
    const int b = blk & 15;                // batch  (blk%8 == b%8 -> XCD lock)
    const int q0 = (blk >> 4) * GQ;        // query tile
    const float* hsb = hs + ((size_t)b * QQ + q0) * CC;

    // ---- Stage 1: GEMMs (waves 0..5) ----
    if (t < 384) {
        float acc[GQ];
#pragma unroll
        for (int g = 0; g < GQ; ++g) acc[g] = 0.f;

        if (t < 256) {
            const int h = t >> 5;
            const int p = (t >> 1) & 15;
            const int xy = t & 1;
            const float* kcol = off_k + t;
#pragma unroll 8
            for (int c = 0; c < CC; ++c) {
                const float k = kcol[c * 256];
#pragma unroll
                for (int g = 0; g < GQ; ++g)
                    acc[g] = fmaf(hsb[g * CC + c], k, acc[g]);
            }
            const float scale = nps[p] * 0.5f;  // OFFSET_SCALE
            const float bias = off_b[t];
            const int didx = ((p * 8 + h) << 1) | xy;
#pragma unroll
            for (int g = 0; g < GQ; ++g) {
                const float4 r = *(const float4*)(refp + ((size_t)b * QQ + q0 + g) * 4);
                const float center = xy ? r.y : r.x;
                const float wh     = xy ? r.w : r.z;
                sh_l[g * 256 + didx] = fmaf((acc[g] + bias) * scale, wh, center);
            }
        } else {
            const int j = t - 256;             // h*16+p
            const int h = j >> 4;
            const int p = j & 15;
            const float* kcol = attn_k + j;
#pragma unroll 8
            for (int c = 0; c < CC; ++c) {
                const float k = kcol[c * 128];
#pragma unroll
                for (int g = 0; g < GQ; ++g)
                    acc[g] = fmaf(hsb[g * CC + c], k, acc[g]);
            }
            const float bias = attn_b[j];
#pragma unroll
            for (int g = 0; g < GQ; ++g) {
                const float logit = acc[g] + bias;
                float m = logit;
#pragma unroll
                for (int o = 1; o < 16; o <<= 1)
                    m = fmaxf(m, __shfl_xor(m, o));
                const float e = __expf(logit - m);
                float s = e;
#pragma unroll
                for (int o = 1; o < 16; o <<= 1)
                    s += __shfl_xor(s, o);
                const float a = e / s;
                attn_out[((size_t)b * QQ + q0 + g) * 128 + j] = a;
                sh_a[g * 128 + p * 8 + h] = a;
            }
        }
    }
    __syncthreads();

    // ---- Stage 2: bilinear weights + corner offsets (1280 tasks) ----
#pragma unroll
    for (int k = 0; k < 2; ++k) {
        const int tau = t + k * 640;       // [q(0..9)][idx(0..127)]
        const int idx = tau & 127;
        const int p = idx >> 3;
        const int lvl = p >> 2;
        const int Wd = 80 >> lvl;
        const float Wf = (float)Wd;
        const int st = (lvl == 0) ? 0 : (lvl == 1) ? 6400 : (lvl == 2) ? 8000 : 8400;

        const float lx_ = sh_l[tau * 2];
        const float ly_ = sh_l[tau * 2 + 1];
        const float a = sh_a[tau];

        const float x = lx_ * Wf - 0.5f;
        const float y = ly_ * Wf - 0.5f;
        const float x0f = floorf(x), y0f = floorf(y);
        const float lx = x - x0f, ly = y - y0f;
        const int x0 = (int)x0f, y0 = (int)y0f;
        const int x1 = x0 + 1, y1 = y0 + 1;

        const bool vx0 = (unsigned)x0 < (unsigned)Wd;
        const bool vx1 = (unsigned)x1 < (unsigned)Wd;
        const bool vy0 = (unsigned)y0 < (unsigned)Wd;
        const bool vy1 = (unsigned)y1 < (unsigned)Wd;

        const int x0c = min(max(x0, 0), Wd - 1);
        const int x1c = min(max(x1, 0), Wd - 1);
        const int y0c = min(max(y0, 0), Wd - 1);
        const int y1c = min(max(y1, 0), Wd - 1);

        float w00 = (1.f - lx) * (1.f - ly) * a;
        float w10 = lx * (1.f - ly) * a;
        float w01 = (1.f - lx) * ly * a;
        float w11 = lx * ly * a;
        w00 = (vx0 & vy0) ? w00 : 0.f;
        w10 = (vx1 & vy0) ? w10 : 0.f;
        w01 = (vx0 & vy1) ? w01 : 0.f;
        w11 = (vx1 & vy1) ? w11 : 0.f;

        const int r0 = (st + y0c * Wd) << 10;   // bytes (1024 B / pixel)
        const int r1 = (st + y1c * Wd) << 10;
        sh_w[tau] = make_float4(w00, w10, w01, w11);
        sh_o[tau] = make_int4(r0 + (x0c << 10), r0 + (x1c << 10),
                              r1 + (x0c << 10), r1 + (x1c << 10));
    }
    __syncthreads();

    // ---- Stage 3: gather + accumulate (wave = query) ----
    const int qs = t >> 6;                 // 0..9
    const int lane = t & 63;
    const int h = lane >> 3;
    const int d4 = (lane & 7) << 2;
    const char* vb = (const char*)(enc + b * (SSS * 256) + h * 32 + d4);

    float4 acc4 = {0.f, 0.f, 0.f, 0.f};

#pragma unroll
    for (int p = 0; p < 16; ++p) {
        const float4 w = sh_w[qs * 128 + p * 8 + h];
        const int4   o = sh_o[qs * 128 + p * 8 + h];
        const float4 v00 = *(const float4*)(vb + o.x);
        const float4 v10 = *(const float4*)(vb + o.y);
        const float4 v01 = *(const float4*)(vb + o.z);
        const float4 v11 = *(const float4*)(vb + o.w);
        acc4.x = fmaf(w.x, v00.x, fmaf(w.y, v10.x, fmaf(w.z, v01.x, fmaf(w.w, v11.x, acc4.x))));
        acc4.y = fmaf(w.x, v00.y, fmaf(w.y, v10.y, fmaf(w.z, v01.y, fmaf(w.w, v11.y, acc4.y))));
        acc4.z = fmaf(w.x, v00.z, fmaf(w.y, v10.z, fmaf(w.z, v01.z, fmaf(w.w, v11.z, acc4.z))));
        acc4.w = fmaf(w.x, v00.w, fmaf(w.y, v10.w, fmaf(w.z, v01.w, fmaf(w.w, v11.w, acc4.w))));
    }

    float* op = out + ((size_t)b * QQ + q0 + qs) * 256 + h * 32 + d4;
    *(float4*)op = acc4;
}

extern "C" void kernel_launch(void* const* d_in, const int* in_sizes, int n_in,
                              void* d_out, int out_size, void* d_ws, size_t ws_size,
                              hipStream_t stream) {
    const float* hs     = (const float*)d_in[0];
    const float* enc    = (const float*)d_in[1];
    const float* refp   = (const float*)d_in[2];
    const float* off_k  = (const float*)d_in[3];
    const float* off_b  = (const float*)d_in[4];
    const float* attn_k = (const float*)d_in[5];
    const float* attn_b = (const float*)d_in[6];
    const float* nps    = (const float*)d_in[7];

    float* out      = (float*)d_out;                  // B*Q*256
    float* attn_out = out + (size_t)BB * QQ * CC;     // B*Q*128

    fused_kernel<<<BB * QT, 640, 0, stream>>>(hs, enc, refp, off_k, off_b,
                                              attn_k, attn_b, nps,
                                              out, attn_out);
}

// Round 6
// 245.160 us; speedup vs baseline: 1.0457x; 1.0457x over previous
//
#include <hip/hip_runtime.h>
#include <math.h>

#define BB 16
#define QQ 300
#define CC 256
#define NHH 8
#define SSS 8500
#define GQ 6
#define QT (QQ / GQ) // 50

// ---------------------------------------------------------------------------
// Kernel A: offsets GEMM + attn GEMM + softmax. GQ=6 (800 blocks) for better
// CU balance than GQ=10's 480. hs reads are block-uniform -> s_load.
// ---------------------------------------------------------------------------
__global__ __launch_bounds__(384) void precompute_kernel(
    const float* __restrict__ hs,      // (B,Q,C)
    const float* __restrict__ refp,    // (B,Q,1,4)
    const float* __restrict__ off_k,   // (C,256)
    const float* __restrict__ off_b,   // 256
    const float* __restrict__ attn_k,  // (C,128)
    const float* __restrict__ attn_b,  // 128
    const float* __restrict__ nps,     // 16
    float* __restrict__ loc_t,         // ws: (B,Q,128,2) [p*8+h][xy]
    float* __restrict__ aw_t,          // ws: (B,Q,128)   [p*8+h]
    float* __restrict__ attn_out)      // d_out: (B,Q,128) [h][p]
{
    const int t = threadIdx.x;
    const int blk = blockIdx.x;            // 0..B*QT-1
    const int b = blk / QT;
    const int q0 = (blk % QT) * GQ;
    const float* hsb = hs + ((size_t)b * QQ + q0) * CC;

    float acc[GQ];
#pragma unroll
    for (int g = 0; g < GQ; ++g) acc[g] = 0.f;

    if (t < 256) {
        const int h = t >> 5;
        const int p = (t >> 1) & 15;
        const int xy = t & 1;
        const float* kcol = off_k + t;
#pragma unroll 8
        for (int c = 0; c < CC; ++c) {
            const float k = kcol[c * 256];
#pragma unroll
            for (int g = 0; g < GQ; ++g)
                acc[g] = fmaf(hsb[g * CC + c], k, acc[g]);
        }
        const float scale = nps[p] * 0.5f;  // OFFSET_SCALE = 0.5
        const float bias = off_b[t];
        const int didx = ((p * 8 + h) << 1) | xy;
#pragma unroll
        for (int g = 0; g < GQ; ++g) {
            const float4 r = *(const float4*)(refp + ((size_t)b * QQ + q0 + g) * 4);
            const float center = xy ? r.y : r.x;
            const float wh     = xy ? r.w : r.z;
            loc_t[((size_t)b * QQ + q0 + g) * 256 + didx] =
                fmaf((acc[g] + bias) * scale, wh, center);
        }
    } else {
        const int j = t - 256;             // 0..127 = h*16+p
        const int h = j >> 4;
        const int p = j & 15;
        const float* kcol = attn_k + j;
#pragma unroll 8
        for (int c = 0; c < CC; ++c) {
            const float k = kcol[c * 128];
#pragma unroll
            for (int g = 0; g < GQ; ++g)
                acc[g] = fmaf(hsb[g * CC + c], k, acc[g]);
        }
        const float bias = attn_b[j];
#pragma unroll
        for (int g = 0; g < GQ; ++g) {
            const float logit = acc[g] + bias;
            float m = logit;
#pragma unroll
            for (int o = 1; o < 16; o <<= 1)
                m = fmaxf(m, __shfl_xor(m, o));
            const float e = __expf(logit - m);
            float s = e;
#pragma unroll
            for (int o = 1; o < 16; o <<= 1)
                s += __shfl_xor(s, o);
            const float a = e / s;
            attn_out[((size_t)b * QQ + q0 + g) * 128 + j] = a;
            aw_t[((size_t)b * QQ + q0 + g) * 128 + p * 8 + h] = a;
        }
    }
}

// ---------------------------------------------------------------------------
// Kernel B v6: two-phase + EXPLICIT double-buffered gather pipeline.
// R5 profile showed VGPR_Count=48 -> only ~2 gathers in flight/thread, pure
// latency exposure (HBM 9%, VALU 12%, occ 26%). Points processed in pairs;
// pair g+1's 8 float4 gathers are issued before pair g is consumed.
// __launch_bounds__(256,4) caps at 128 VGPR (grid already limits to ~4.7
// waves/SIMD, so no occupancy loss) and frees the allocator to hold both
// buffers (~100 VGPR).
// ---------------------------------------------------------------------------
struct Pair { float4 w[2]; int4 o[2]; };

__device__ __forceinline__ void fetch_meta(const float4* __restrict__ shw,
                                           const int4* __restrict__ sho,
                                           int base, int g, Pair& pr) {
#pragma unroll
    for (int j = 0; j < 2; ++j) {
        pr.w[j] = shw[base + (2 * g + j) * 8];
        pr.o[j] = sho[base + (2 * g + j) * 8];
    }
}

__device__ __forceinline__ void fetch_vals(const char* __restrict__ vb,
                                           const Pair& pr, float4 v[8]) {
#pragma unroll
    for (int j = 0; j < 2; ++j) {
        v[j * 4 + 0] = *(const float4*)(vb + pr.o[j].x);
        v[j * 4 + 1] = *(const float4*)(vb + pr.o[j].y);
        v[j * 4 + 2] = *(const float4*)(vb + pr.o[j].z);
        v[j * 4 + 3] = *(const float4*)(vb + pr.o[j].w);
    }
}

__device__ __forceinline__ void consume(const Pair& pr, const float4 v[8],
                                        float4& acc) {
#pragma unroll
    for (int j = 0; j < 2; ++j) {
        const float4 w = pr.w[j];
        acc.x = fmaf(w.x, v[j*4+0].x, fmaf(w.y, v[j*4+1].x, fmaf(w.z, v[j*4+2].x, fmaf(w.w, v[j*4+3].x, acc.x))));
        acc.y = fmaf(w.x, v[j*4+0].y, fmaf(w.y, v[j*4+1].y, fmaf(w.z, v[j*4+2].y, fmaf(w.w, v[j*4+3].y, acc.y))));
        acc.z = fmaf(w.x, v[j*4+0].z, fmaf(w.y, v[j*4+1].z, fmaf(w.z, v[j*4+2].z, fmaf(w.w, v[j*4+3].z, acc.z))));
        acc.w = fmaf(w.x, v[j*4+0].w, fmaf(w.y, v[j*4+1].w, fmaf(w.z, v[j*4+2].w, fmaf(w.w, v[j*4+3].w, acc.w))));
    }
}

__global__ __launch_bounds__(256, 4) void sample_kernel(
    const float* __restrict__ enc,    // (B,S,256)
    const float2* __restrict__ loc2,  // (B,Q,128) float2, [p*8+h]
    const float* __restrict__ aw_t,   // (B,Q,128), [p*8+h]
    float* __restrict__ out)          // (B,Q,256)
{
    __shared__ float4 sh_w[4 * 128];  // [qs][p*8+h] = {w00,w10,w01,w11}
    __shared__ int4   sh_o[4 * 128];  // [qs][p*8+h] = corner byte offsets

    const int g = blockIdx.x;              // 0..1199
    const int xcd = g & 7;
    const int i = g >> 3;                  // 0..149
    const int b = ((i & 1) << 3) | xcd;    // batch (XCD-locked)
    const int q0 = (i >> 1) * 4;           // 0..296
    const int qbase = b * QQ + q0;

    const int t = threadIdx.x;

    // ---- Phase 1: 512 (q,h,p) tasks, 2/thread: weights + corner offsets ----
#pragma unroll
    for (int k = 0; k < 2; ++k) {
        const int tau = t + k * 256;       // qs = tau>>7, idx = tau&127
        const int idx = tau & 127;
        const int p = idx >> 3;
        const int lvl = p >> 2;
        const int Wd = 80 >> lvl;
        const float Wf = (float)Wd;
        const int st = (lvl == 0) ? 0 : (lvl == 1) ? 6400 : (lvl == 2) ? 8000 : 8400;

        const float2 l = loc2[(size_t)qbase * 128 + tau];
        const float  a = aw_t[(size_t)qbase * 128 + tau];

        const float x = l.x * Wf - 0.5f;
        const float y = l.y * Wf - 0.5f;
        const float x0f = floorf(x), y0f = floorf(y);
        const float lx = x - x0f, ly = y - y0f;
        const int x0 = (int)x0f, y0 = (int)y0f;
        const int x1 = x0 + 1, y1 = y0 + 1;

        const bool vx0 = (unsigned)x0 < (unsigned)Wd;
        const bool vx1 = (unsigned)x1 < (unsigned)Wd;
        const bool vy0 = (unsigned)y0 < (unsigned)Wd;
        const bool vy1 = (unsigned)y1 < (unsigned)Wd;

        const int x0c = min(max(x0, 0), Wd - 1);
        const int x1c = min(max(x1, 0), Wd - 1);
        const int y0c = min(max(y0, 0), Wd - 1);
        const int y1c = min(max(y1, 0), Wd - 1);

        float w00 = (1.f - lx) * (1.f - ly) * a;
        float w10 = lx * (1.f - ly) * a;
        float w01 = (1.f - lx) * ly * a;
        float w11 = lx * ly * a;
        w00 = (vx0 & vy0) ? w00 : 0.f;
        w10 = (vx1 & vy0) ? w10 : 0.f;
        w01 = (vx0 & vy1) ? w01 : 0.f;
        w11 = (vx1 & vy1) ? w11 : 0.f;

        const int r0 = (st + y0c * Wd) << 10;   // byte offsets (1024 B/pixel)
        const int r1 = (st + y1c * Wd) << 10;
        sh_w[tau] = make_float4(w00, w10, w01, w11);
        sh_o[tau] = make_int4(r0 + (x0c << 10), r0 + (x1c << 10),
                              r1 + (x0c << 10), r1 + (x1c << 10));
    }
    __syncthreads();

    // ---- Phase 2: wave=query; software-pipelined pairs of points ----
    const int qs = t >> 6;
    const int lane = t & 63;
    const int h = lane >> 3;
    const int d4 = (lane & 7) << 2;
    const char* vb = (const char*)(enc + b * (SSS * 256) + h * 32 + d4);
    const int base = qs * 128 + h;

    float4 acc = {0.f, 0.f, 0.f, 0.f};

    Pair prA, prB;
    float4 vA[8], vB[8];

    fetch_meta(sh_w, sh_o, base, 0, prA);
    fetch_vals(vb, prA, vA);
    fetch_meta(sh_w, sh_o, base, 1, prB);
    fetch_vals(vb, prB, vB);

#pragma unroll
    for (int gp = 0; gp < 6; ++gp) {
        if ((gp & 1) == 0) {
            consume(prA, vA, acc);                 // waits on vA only
            fetch_meta(sh_w, sh_o, base, gp + 2, prA);
            fetch_vals(vb, prA, vA);               // refill while vB in flight
        } else {
            consume(prB, vB, acc);
            fetch_meta(sh_w, sh_o, base, gp + 2, prB);
            fetch_vals(vb, prB, vB);
        }
    }
    consume(prA, vA, acc);
    consume(prB, vB, acc);

    float* op = out + (size_t)(qbase + qs) * 256 + h * 32 + d4;
    *(float4*)op = acc;
}

extern "C" void kernel_launch(void* const* d_in, const int* in_sizes, int n_in,
                              void* d_out, int out_size, void* d_ws, size_t ws_size,
                              hipStream_t stream) {
    const float* hs     = (const float*)d_in[0];
    const float* enc    = (const float*)d_in[1];
    const float* refp   = (const float*)d_in[2];
    const float* off_k  = (const float*)d_in[3];
    const float* off_b  = (const float*)d_in[4];
    const float* attn_k = (const float*)d_in[5];
    const float* attn_b = (const float*)d_in[6];
    const float* nps    = (const float*)d_in[7];

    float* out      = (float*)d_out;                       // B*Q*256
    float* attn_out = out + (size_t)BB * QQ * CC;          // B*Q*128
    float* loc_t    = (float*)d_ws;                        // B*Q*256 floats
    float* aw_t     = loc_t + (size_t)BB * QQ * 256;       // B*Q*128 floats

    precompute_kernel<<<BB * QT, 384, 0, stream>>>(hs, refp, off_k, off_b,
                                                   attn_k, attn_b, nps,
                                                   loc_t, aw_t, attn_out);
    sample_kernel<<<BB * (QQ / 4), 256, 0, stream>>>(enc, (const float2*)loc_t,
                                                     aw_t, out);
}